// Round 6
// baseline (3605.361 us; speedup 1.0000x reference)
//
#include <hip/hip_runtime.h>
#include <hip/hip_bf16.h>

#define BATCH 4096
#define DIM   512
#define HID   2048
#define NSTEPS 20

typedef __attribute__((ext_vector_type(8))) short short8;
typedef __attribute__((ext_vector_type(4))) short short4v;
typedef __attribute__((ext_vector_type(4))) float floatx4;

#define GLL(dst, src) __builtin_amdgcn_global_load_lds( \
    (const __attribute__((address_space(1))) void*)(src), \
    (__attribute__((address_space(3))) void*)(dst), 16, 0, 0)

__device__ __forceinline__ short f2bf(float x) {
    union { float f; unsigned u; } v; v.f = x;
    unsigned r = v.u + 0x7fffu + ((v.u >> 16) & 1u);
    return (short)(r >> 16);
}

// tanh(x) = 1 - 2*rcp(1 + exp2(2*log2e*x)); saturates correctly at +-inf
__device__ __forceinline__ float fast_tanh(float x) {
    float e = __builtin_amdgcn_exp2f(x * 2.8853900817779268f);
    float r = __builtin_amdgcn_rcpf(1.0f + e);
    return 1.0f - 2.0f * r;
}

// dst[n][k] = bf16(src[k][n]); src is K x N row-major fp32
__global__ void transpose_cvt(const float* __restrict__ src, short* __restrict__ dst,
                              int K, int N) {
    __shared__ float tile[32][33];
    int k0 = blockIdx.x * 32, n0 = blockIdx.y * 32;
    int tx = threadIdx.x, ty = threadIdx.y;
    #pragma unroll
    for (int r = ty; r < 32; r += 8)
        tile[r][tx] = src[(size_t)(k0 + r) * N + n0 + tx];
    __syncthreads();
    #pragma unroll
    for (int r = ty; r < 32; r += 8)
        dst[(size_t)(n0 + r) * K + k0 + tx] = f2bf(tile[tx][r]);
}

__global__ void extract_row(const float* __restrict__ W1, float* __restrict__ w1last) {
    int i = blockIdx.x * 256 + threadIdx.x;
    w1last[i] = W1[(size_t)DIM * HID + i];
}

__global__ void init_abuf(const float* __restrict__ z0, short* __restrict__ abuf) {
    size_t i = (size_t)(blockIdx.x * 256 + threadIdx.x) * 4;
    float4 zv = *(const float4*)(z0 + i);
    short4v o;
    o[0] = f2bf(zv.x); o[1] = f2bf(zv.y); o[2] = f2bf(zv.z); o[3] = f2bf(zv.w);
    *(short4v*)(abuf + i) = o;
}

// hidden = tanh( A @ W1t^T + b1 + t*w1last ), bf16 out.
// 128x128 tile, BK=64, XOR swizzle, double-buffered LDS; barrier-based sync only
// (compiler drains vmcnt(0) at each s_barrier -> prefetch has a full compute
// phase to land; race-free by construction, m99/m100 pattern).
__global__ __launch_bounds__(256, 2)
void gemm1_tanh(const short* __restrict__ A, const short* __restrict__ Bt,
                const float* __restrict__ b1, const float* __restrict__ w1last,
                const float* __restrict__ t0p, const float* __restrict__ t1p,
                float c_t, float step_i,
                short* __restrict__ hidden) {
    __shared__ short Alds[2][128 * 64];   // 2 x 16 KB
    __shared__ short Blds[2][128 * 64];   // 2 x 16 KB
    const int tid = threadIdx.x;
    const int lane = tid & 63;
    const int wave = tid >> 6;
    const int wm = wave >> 1, wn = wave & 1;
    const int bm0 = blockIdx.x * 128;
    const int bn0 = blockIdx.y * 128;

    const float t0 = t0p[0], t1 = t1p[0];
    const float h = (t1 - t0) / (float)NSTEPS;
    const float teval = t0 + (step_i + c_t) * h;

    floatx4 acc[4][4];
    #pragma unroll
    for (int i = 0; i < 4; i++)
        #pragma unroll
        for (int j = 0; j < 4; j++) acc[i][j] = (floatx4)0.f;

    const int fr = lane & 15;
    const int fkc = lane >> 4;     // 0..3
    const int rx = fr & 7;

    auto stage = [&](int it, int bufi) {
        const int kk = it * 64;
        #pragma unroll
        for (int p = 0; p < 4; p++) {
            int c = tid + p * 256;
            int row = c >> 3;
            int g = (c & 7) ^ (row & 7);   // swizzled global k-chunk
            GLL(&Alds[bufi][c * 8], A  + (size_t)(bm0 + row) * DIM + kk + g * 8);
            GLL(&Blds[bufi][c * 8], Bt + (size_t)(bn0 + row) * DIM + kk + g * 8);
        }
    };

    stage(0, 0);
    for (int it = 0; it < 8; ++it) {
        __syncthreads();               // drains prefetch issued one compute-phase ago
        if (it < 7) stage(it + 1, (it + 1) & 1);
        const short* Ab = Alds[it & 1];
        const short* Bb = Blds[it & 1];
        #pragma unroll
        for (int s = 0; s < 2; s++) {
            const int slot = ((s * 4 + fkc) ^ rx) * 8;
            short8 af[4], bfr[4];
            #pragma unroll
            for (int mt = 0; mt < 4; mt++)
                af[mt] = *(const short8*)&Ab[(wm * 64 + mt * 16 + fr) * 64 + slot];
            #pragma unroll
            for (int nt = 0; nt < 4; nt++)
                bfr[nt] = *(const short8*)&Bb[(wn * 64 + nt * 16 + fr) * 64 + slot];
            #pragma unroll
            for (int mt = 0; mt < 4; mt++)
                #pragma unroll
                for (int nt = 0; nt < 4; nt++)   // swapped operands -> transposed C layout
                    acc[mt][nt] = __builtin_amdgcn_mfma_f32_16x16x32_bf16(bfr[nt], af[mt], acc[mt][nt], 0, 0, 0);
        }
    }
    // epilogue: lane = row m (fr); regs = 4 consecutive cols n -> packed 8B stores
    #pragma unroll
    for (int mt = 0; mt < 4; mt++) {
        int m = bm0 + wm * 64 + mt * 16 + fr;
        short* hrow = hidden + (size_t)m * HID;
        #pragma unroll
        for (int nt = 0; nt < 4; nt++) {
            int n0 = bn0 + wn * 64 + nt * 16 + fkc * 4;
            float4 bb = *(const float4*)&b1[n0];
            float4 wl = *(const float4*)&w1last[n0];
            short4v o;
            o[0] = f2bf(fast_tanh(acc[mt][nt][0] + bb.x + teval * wl.x));
            o[1] = f2bf(fast_tanh(acc[mt][nt][1] + bb.y + teval * wl.y));
            o[2] = f2bf(fast_tanh(acc[mt][nt][2] + bb.z + teval * wl.z));
            o[3] = f2bf(fast_tanh(acc[mt][nt][3] + bb.w + teval * wl.w));
            *(short4v*)&hrow[n0] = o;
        }
    }
}

// k = hidden @ W2t^T + b2.  64x64 tile, 4-way K-split across waves (wave-tile
// 64x64 over K=512), per-wave private LDS slabs, double-buffered, BK=32.
// Sync is BARRIER-BASED only (same safe pattern as gemm1): prefetch issued after
// __syncthreads, consumed after the next __syncthreads' forced vmcnt(0) drain.
// mode 0 (k1): kacc = k;            abuf = bf16(z + alpha*h*k)
// mode 1 (k2/k3): kacc += wk*k;     abuf = bf16(z + alpha*h*k)
// mode 2 (k4): z += (h/6)*(kacc+k); abuf = bf16(z_new)
__global__ __launch_bounds__(256, 2)
void gemm2_fused(const short* __restrict__ hidden,  // [BATCH][HID] bf16
                 const short* __restrict__ Bt,      // W2t [DIM][HID] bf16
                 const float* __restrict__ b2,
                 float* __restrict__ z,
                 float* __restrict__ kacc, short* __restrict__ abuf,
                 const float* __restrict__ t0p, const float* __restrict__ t1p,
                 int mode, float wk, float alpha_c) {
    __shared__ short lds[32768];        // 64 KB: 4 waves x 2 bufs x (A 4KB + B 4KB)
    const int tid = threadIdx.x;
    const int lane = tid & 63;
    const int wave = tid >> 6;          // K-split index
    const int bm0 = blockIdx.x * 64;    // 64 blocks over M
    const int bn0 = blockIdx.y * 64;    // 8 blocks over N
    const int kbase = wave * 512;
    short* wbase = &lds[wave * 8192];   // 16 KB per wave

    const int fr = lane & 15;
    const int fkc = lane >> 4;          // 0..3
    const int l2r = lane >> 2;          // 0..15
    const int lch = lane & 3;           // 0..3

    floatx4 acc[4][4];
    #pragma unroll
    for (int i = 0; i < 4; i++)
        #pragma unroll
        for (int j = 0; j < 4; j++) acc[i][j] = (floatx4)0.f;

    auto issue = [&](int it, int bufi) {
        short* sA = wbase + bufi * 4096;   // 8 KB buf: A 64x32 + B 64x32
        short* sB = sA + 2048;
        const int k0 = kbase + it * 32;
        #pragma unroll
        for (int j = 0; j < 4; j++) {
            int row = j * 16 + l2r;
            GLL(&sA[j * 512 + lane * 8], hidden + (size_t)(bm0 + row) * HID + k0 + lch * 8);
            GLL(&sB[j * 512 + lane * 8], Bt     + (size_t)(bn0 + row) * HID + k0 + lch * 8);
        }
    };

    issue(0, 0);
    for (int it = 0; it < 16; ++it) {
        __syncthreads();               // forced vmcnt(0): prefetch from prev iter landed
        if (it < 15) issue(it + 1, (it + 1) & 1);
        const short* sA = wbase + (it & 1) * 4096;
        const short* sB = sA + 2048;
        short8 af[4], bfr[4];
        #pragma unroll
        for (int mt = 0; mt < 4; mt++)
            af[mt] = *(const short8*)&sA[(mt * 16 + fr) * 32 + fkc * 8];
        #pragma unroll
        for (int nt = 0; nt < 4; nt++)
            bfr[nt] = *(const short8*)&sB[(nt * 16 + fr) * 32 + fkc * 8];
        #pragma unroll
        for (int mt = 0; mt < 4; mt++)
            #pragma unroll
            for (int nt = 0; nt < 4; nt++)
                acc[mt][nt] = __builtin_amdgcn_mfma_f32_16x16x32_bf16(af[mt], bfr[nt], acc[mt][nt], 0, 0, 0);
    }

    // write partial acc (fp32 [64][64]) into own 16 KB region, reduce across 4 waves
    __syncthreads();                   // all waves done with slab reads
    float* fslab = (float*)wbase;
    #pragma unroll
    for (int mt = 0; mt < 4; mt++)
        #pragma unroll
        for (int nt = 0; nt < 4; nt++)
            #pragma unroll
            for (int r = 0; r < 4; r++) {
                int row = mt * 16 + fkc * 4 + r;
                int col = nt * 16 + fr;
                fslab[row * 64 + col] = acc[mt][nt][r];
            }
    __syncthreads();

    const int rrow = tid >> 2;
    const int cb = (tid & 3) * 16;
    float4 v[4];
    #pragma unroll
    for (int ch = 0; ch < 4; ch++) v[ch] = make_float4(0.f, 0.f, 0.f, 0.f);
    #pragma unroll
    for (int w = 0; w < 4; w++) {
        const float* fs = (const float*)&lds[w * 8192];
        #pragma unroll
        for (int ch = 0; ch < 4; ch++) {
            float4 p = *(const float4*)&fs[rrow * 64 + cb + ch * 4];
            v[ch].x += p.x; v[ch].y += p.y; v[ch].z += p.z; v[ch].w += p.w;
        }
    }

    const float h = (t1p[0] - t0p[0]) / (float)NSTEPS;
    const float ah = alpha_c * h;
    const float h6 = h / 6.0f;
    const size_t base = (size_t)(bm0 + rrow) * DIM + bn0 + cb;
    #pragma unroll
    for (int ch = 0; ch < 4; ch++) {
        float4 bb = *(const float4*)&b2[bn0 + cb + ch * 4];
        float kv[4] = { v[ch].x + bb.x, v[ch].y + bb.y, v[ch].z + bb.z, v[ch].w + bb.w };
        size_t idx = base + ch * 4;
        float4 zv = *(const float4*)&z[idx];
        float zn[4];
        if (mode == 0) {
            *(float4*)&kacc[idx] = make_float4(kv[0], kv[1], kv[2], kv[3]);
            zn[0] = zv.x + ah * kv[0]; zn[1] = zv.y + ah * kv[1];
            zn[2] = zv.z + ah * kv[2]; zn[3] = zv.w + ah * kv[3];
        } else if (mode == 1) {
            float4 ka = *(const float4*)&kacc[idx];
            *(float4*)&kacc[idx] = make_float4(ka.x + wk * kv[0], ka.y + wk * kv[1],
                                               ka.z + wk * kv[2], ka.w + wk * kv[3]);
            zn[0] = zv.x + ah * kv[0]; zn[1] = zv.y + ah * kv[1];
            zn[2] = zv.z + ah * kv[2]; zn[3] = zv.w + ah * kv[3];
        } else {
            float4 ka = *(const float4*)&kacc[idx];
            zn[0] = zv.x + h6 * (ka.x + kv[0]); zn[1] = zv.y + h6 * (ka.y + kv[1]);
            zn[2] = zv.z + h6 * (ka.z + kv[2]); zn[3] = zv.w + h6 * (ka.w + kv[3]);
            *(float4*)&z[idx] = make_float4(zn[0], zn[1], zn[2], zn[3]);
        }
        short4v o;
        o[0] = f2bf(zn[0]); o[1] = f2bf(zn[1]); o[2] = f2bf(zn[2]); o[3] = f2bf(zn[3]);
        *(short4v*)&abuf[idx] = o;
    }
}

extern "C" void kernel_launch(void* const* d_in, const int* in_sizes, int n_in,
                              void* d_out, int out_size, void* d_ws, size_t ws_size,
                              hipStream_t stream) {
    const float* z0  = (const float*)d_in[0];
    const float* W1  = (const float*)d_in[1];
    const float* b1  = (const float*)d_in[2];
    const float* W2  = (const float*)d_in[3];
    const float* b2  = (const float*)d_in[4];
    const float* t0p = (const float*)d_in[5];
    const float* t1p = (const float*)d_in[6];
    float* z = (float*)d_out;

    char* ws = (char*)d_ws;
    short* W1t    = (short*)(ws);                              // 2 MB
    short* W2t    = (short*)(ws + (2u << 20));                 // 2 MB
    float* w1last = (float*)(ws + (4u << 20));                 // 8 KB (pad 64 KB)
    short* abuf   = (short*)(ws + (4u << 20) + (1u << 16));    // 4 MB
    short* hidden = (short*)(ws + (8u << 20) + (1u << 16));    // 16 MB
    float* kacc   = (float*)(ws + (24u << 20) + (1u << 16));   // 8 MB

    hipMemcpyAsync(z, z0, (size_t)BATCH * DIM * sizeof(float),
                   hipMemcpyDeviceToDevice, stream);
    transpose_cvt<<<dim3(DIM / 32, HID / 32), dim3(32, 8), 0, stream>>>(W1, W1t, DIM, HID);
    transpose_cvt<<<dim3(HID / 32, DIM / 32), dim3(32, 8), 0, stream>>>(W2, W2t, HID, DIM);
    extract_row<<<HID / 256, 256, 0, stream>>>(W1, w1last);
    init_abuf<<<BATCH * DIM / 4 / 256, 256, 0, stream>>>(z0, abuf);

    const dim3 g1(BATCH / 128, HID / 128), g2(BATCH / 64, DIM / 64), b(256);
    for (int i = 0; i < NSTEPS; i++) {
        float fi = (float)i;
        // k1 -> abuf for k2
        gemm1_tanh<<<g1, b, 0, stream>>>(abuf, W1t, b1, w1last, t0p, t1p, 0.0f, fi, hidden);
        gemm2_fused<<<g2, b, 0, stream>>>(hidden, W2t, b2, z, kacc, abuf, t0p, t1p, 0, 1.0f, 0.5f);
        // k2 -> abuf for k3
        gemm1_tanh<<<g1, b, 0, stream>>>(abuf, W1t, b1, w1last, t0p, t1p, 0.5f, fi, hidden);
        gemm2_fused<<<g2, b, 0, stream>>>(hidden, W2t, b2, z, kacc, abuf, t0p, t1p, 1, 2.0f, 0.5f);
        // k3 -> abuf for k4
        gemm1_tanh<<<g1, b, 0, stream>>>(abuf, W1t, b1, w1last, t0p, t1p, 0.5f, fi, hidden);
        gemm2_fused<<<g2, b, 0, stream>>>(hidden, W2t, b2, z, kacc, abuf, t0p, t1p, 1, 2.0f, 1.0f);
        // k4: z += (h/6)*(kacc + k4) ; abuf = bf16(z_new)
        gemm1_tanh<<<g1, b, 0, stream>>>(abuf, W1t, b1, w1last, t0p, t1p, 1.0f, fi, hidden);
        gemm2_fused<<<g2, b, 0, stream>>>(hidden, W2t, b2, z, kacc, abuf, t0p, t1p, 2, 1.0f, 0.0f);
    }
}

// Round 7
// 3144.557 us; speedup vs baseline: 1.1465x; 1.1465x over previous
//
#include <hip/hip_runtime.h>
#include <hip/hip_bf16.h>

#define BATCH 4096
#define DIM   512
#define HID   2048
#define NSTEPS 20

typedef __attribute__((ext_vector_type(8))) short short8;
typedef __attribute__((ext_vector_type(4))) short short4v;
typedef __attribute__((ext_vector_type(4))) float floatx4;

#define GLL(dst, src) __builtin_amdgcn_global_load_lds( \
    (const __attribute__((address_space(1))) void*)(src), \
    (__attribute__((address_space(3))) void*)(dst), 16, 0, 0)

__device__ __forceinline__ short f2bf(float x) {
    union { float f; unsigned u; } v; v.f = x;
    unsigned r = v.u + 0x7fffu + ((v.u >> 16) & 1u);
    return (short)(r >> 16);
}

// tanh(x) = 1 - 2*rcp(1 + exp2(2*log2e*x)); saturates correctly at +-inf
__device__ __forceinline__ float fast_tanh(float x) {
    float e = __builtin_amdgcn_exp2f(x * 2.8853900817779268f);
    float r = __builtin_amdgcn_rcpf(1.0f + e);
    return 1.0f - 2.0f * r;
}

// dst[n][k] = bf16(src[k][n]); src is K x N row-major fp32
__global__ void transpose_cvt(const float* __restrict__ src, short* __restrict__ dst,
                              int K, int N) {
    __shared__ float tile[32][33];
    int k0 = blockIdx.x * 32, n0 = blockIdx.y * 32;
    int tx = threadIdx.x, ty = threadIdx.y;
    #pragma unroll
    for (int r = ty; r < 32; r += 8)
        tile[r][tx] = src[(size_t)(k0 + r) * N + n0 + tx];
    __syncthreads();
    #pragma unroll
    for (int r = ty; r < 32; r += 8)
        dst[(size_t)(n0 + r) * K + k0 + tx] = f2bf(tile[tx][r]);
}

__global__ void extract_row(const float* __restrict__ W1, float* __restrict__ w1last) {
    int i = blockIdx.x * 256 + threadIdx.x;
    w1last[i] = W1[(size_t)DIM * HID + i];
}

__global__ void init_abuf(const float* __restrict__ z0, short* __restrict__ abuf) {
    size_t i = (size_t)(blockIdx.x * 256 + threadIdx.x) * 4;
    float4 zv = *(const float4*)(z0 + i);
    short4v o;
    o[0] = f2bf(zv.x); o[1] = f2bf(zv.y); o[2] = f2bf(zv.z); o[3] = f2bf(zv.w);
    *(short4v*)(abuf + i) = o;
}

// hidden = tanh( A @ W1t^T + b1 + t*w1last ), bf16 out.
// 128x64 tile, BK=64, XOR swizzle, single-buffered, grid 1024 -> 4 blocks/CU
// (24 KB LDS, VGPR-capped by launch_bounds(256,4)). Barrier drains overlap
// across the 4 resident blocks (m114 implicit wave-level overlap).
__global__ __launch_bounds__(256, 4)
void gemm1_tanh(const short* __restrict__ A, const short* __restrict__ Bt,
                const float* __restrict__ b1, const float* __restrict__ w1last,
                const float* __restrict__ t0p, const float* __restrict__ t1p,
                float c_t, float step_i,
                short* __restrict__ hidden) {
    __shared__ short Alds[128 * 64];   // 16 KB
    __shared__ short Blds[64 * 64];    // 8 KB
    const int tid = threadIdx.x;
    const int lane = tid & 63;
    const int wave = tid >> 6;
    const int wm = wave >> 1, wn = wave & 1;   // wave-tile 64M x 32N
    const int bm0 = blockIdx.x * 128;   // 32 blocks over M
    const int bn0 = blockIdx.y * 64;    // 32 blocks over N

    const float t0 = t0p[0], t1 = t1p[0];
    const float h = (t1 - t0) / (float)NSTEPS;
    const float teval = t0 + (step_i + c_t) * h;

    floatx4 acc[4][2];
    #pragma unroll
    for (int i = 0; i < 4; i++) {
        acc[i][0] = (floatx4)0.f;
        acc[i][1] = (floatx4)0.f;
    }

    const int fr = lane & 15;
    const int fkc = lane >> 4;     // 0..3
    const int rx = fr & 7;

    for (int kk = 0; kk < DIM; kk += 64) {
        // stage A tile 128x64 (1024 16B-chunks) + B tile 64x64 (512 chunks)
        #pragma unroll
        for (int p = 0; p < 4; p++) {
            int c = tid + p * 256;
            int row = c >> 3;
            int g = (c & 7) ^ (row & 7);   // swizzled global k-chunk
            GLL(&Alds[c * 8], A + (size_t)(bm0 + row) * DIM + kk + g * 8);
        }
        #pragma unroll
        for (int p = 0; p < 2; p++) {
            int c = tid + p * 256;
            int row = c >> 3;
            int g = (c & 7) ^ (row & 7);
            GLL(&Blds[c * 8], Bt + (size_t)(bn0 + row) * DIM + kk + g * 8);
        }
        __syncthreads();               // forced vmcnt(0): staging landed
        #pragma unroll
        for (int s = 0; s < 2; s++) {
            const int slot = ((s * 4 + fkc) ^ rx) * 8;
            short8 bfr[2];
            #pragma unroll
            for (int nt = 0; nt < 2; nt++)
                bfr[nt] = *(const short8*)&Blds[(wn * 32 + nt * 16 + fr) * 64 + slot];
            #pragma unroll
            for (int mt = 0; mt < 4; mt++) {
                short8 af = *(const short8*)&Alds[(wm * 64 + mt * 16 + fr) * 64 + slot];
                #pragma unroll
                for (int nt = 0; nt < 2; nt++)   // swapped operands -> lane holds 4 cols
                    acc[mt][nt] = __builtin_amdgcn_mfma_f32_16x16x32_bf16(bfr[nt], af, acc[mt][nt], 0, 0, 0);
            }
        }
        __syncthreads();
    }
    // epilogue: lane = row m (fr); regs = 4 consecutive cols -> packed 8B stores
    #pragma unroll
    for (int mt = 0; mt < 4; mt++) {
        int m = bm0 + wm * 64 + mt * 16 + fr;
        short* hrow = hidden + (size_t)m * HID;
        #pragma unroll
        for (int nt = 0; nt < 2; nt++) {
            int n0 = bn0 + wn * 32 + nt * 16 + fkc * 4;
            float4 bb = *(const float4*)&b1[n0];
            float4 wl = *(const float4*)&w1last[n0];
            short4v o;
            o[0] = f2bf(fast_tanh(acc[mt][nt][0] + bb.x + teval * wl.x));
            o[1] = f2bf(fast_tanh(acc[mt][nt][1] + bb.y + teval * wl.y));
            o[2] = f2bf(fast_tanh(acc[mt][nt][2] + bb.z + teval * wl.z));
            o[3] = f2bf(fast_tanh(acc[mt][nt][3] + bb.w + teval * wl.w));
            *(short4v*)&hrow[n0] = o;
        }
    }
}

// k = hidden @ W2t^T + b2.  64x64 tile, 4-way K-split across waves (wave-tile
// 64x64 over K=512), per-wave private LDS slab, NO barriers in K-loop
// (per-wave vmcnt(0) only).  == R4 kernel verbatim (proven correct+fastest).
// mode 0 (k1): kacc = k;            abuf = bf16(z + alpha*h*k)
// mode 1 (k2/k3): kacc += wk*k;     abuf = bf16(z + alpha*h*k)
// mode 2 (k4): z += (h/6)*(kacc+k); abuf = bf16(z_new)
__global__ __launch_bounds__(256, 2)
void gemm2_fused(const short* __restrict__ hidden,  // [BATCH][HID] bf16
                 const short* __restrict__ Bt,      // W2t [DIM][HID] bf16
                 const float* __restrict__ b2,
                 float* __restrict__ z,
                 float* __restrict__ kacc, short* __restrict__ abuf,
                 const float* __restrict__ t0p, const float* __restrict__ t1p,
                 int mode, float wk, float alpha_c) {
    __shared__ short lds[4 * 8192];    // 4 slabs x 16 KB (A[64][64] + B[64][64])
    const int tid = threadIdx.x;
    const int lane = tid & 63;
    const int wave = tid >> 6;          // K-split index
    const int bm0 = blockIdx.x * 64;    // 64 blocks over M
    const int bn0 = blockIdx.y * 64;    // 8 blocks over N
    const int kbase = wave * 512;

    short* slabA = &lds[wave * 8192];
    short* slabB = slabA + 4096;

    const int fr = lane & 15;
    const int fkc = lane >> 4;     // 0..3
    const int rx = fr & 7;
    const int l3 = lane >> 3;      // 0..7
    const int gch = (lane & 7) ^ l3;   // swizzled global k-chunk for staging

    floatx4 acc[4][4];
    #pragma unroll
    for (int i = 0; i < 4; i++)
        #pragma unroll
        for (int j = 0; j < 4; j++) acc[i][j] = (floatx4)0.f;

    for (int kk = 0; kk < 512; kk += 64) {
        const int k0 = kbase + kk;
        // drain own ds_reads before overwriting slab (lgkmcnt(0), vmcnt don't-care)
        __builtin_amdgcn_s_waitcnt(0xC07F);
        #pragma unroll
        for (int j = 0; j < 8; j++) {
            int row = j * 8 + l3;
            GLL(&slabA[j * 512 + lane * 8], hidden + (size_t)(bm0 + row) * HID + k0 + gch * 8);
            GLL(&slabB[j * 512 + lane * 8], Bt     + (size_t)(bn0 + row) * HID + k0 + gch * 8);
        }
        __builtin_amdgcn_sched_barrier(0);
        __builtin_amdgcn_s_waitcnt(0x0F70);   // vmcnt(0) only, per-wave
        __builtin_amdgcn_sched_barrier(0);
        #pragma unroll
        for (int s = 0; s < 2; s++) {
            const int slot = ((s * 4 + fkc) ^ rx) * 8;
            short8 af[4], bfr[4];
            #pragma unroll
            for (int mt = 0; mt < 4; mt++)
                af[mt] = *(const short8*)&slabA[(mt * 16 + fr) * 64 + slot];
            #pragma unroll
            for (int nt = 0; nt < 4; nt++)
                bfr[nt] = *(const short8*)&slabB[(nt * 16 + fr) * 64 + slot];
            #pragma unroll
            for (int mt = 0; mt < 4; mt++)
                #pragma unroll
                for (int nt = 0; nt < 4; nt++)
                    acc[mt][nt] = __builtin_amdgcn_mfma_f32_16x16x32_bf16(af[mt], bfr[nt], acc[mt][nt], 0, 0, 0);
        }
        __builtin_amdgcn_sched_barrier(0);
    }

    // write partial acc (fp32 [64][64]) into own slab, then reduce across 4 waves
    float* fslab = (float*)slabA;
    #pragma unroll
    for (int mt = 0; mt < 4; mt++)
        #pragma unroll
        for (int nt = 0; nt < 4; nt++)
            #pragma unroll
            for (int r = 0; r < 4; r++) {
                int row = mt * 16 + fkc * 4 + r;
                int col = nt * 16 + fr;
                fslab[row * 64 + col] = acc[mt][nt][r];
            }
    __syncthreads();

    const int rrow = tid >> 2;
    const int cb = (tid & 3) * 16;
    float4 v[4];
    #pragma unroll
    for (int ch = 0; ch < 4; ch++) v[ch] = make_float4(0.f, 0.f, 0.f, 0.f);
    #pragma unroll
    for (int w = 0; w < 4; w++) {
        const float* fs = (const float*)&lds[w * 8192];
        #pragma unroll
        for (int ch = 0; ch < 4; ch++) {
            float4 p = *(const float4*)&fs[rrow * 64 + cb + ch * 4];
            v[ch].x += p.x; v[ch].y += p.y; v[ch].z += p.z; v[ch].w += p.w;
        }
    }

    const float h = (t1p[0] - t0p[0]) / (float)NSTEPS;
    const float ah = alpha_c * h;
    const float h6 = h / 6.0f;
    const size_t base = (size_t)(bm0 + rrow) * DIM + bn0 + cb;
    #pragma unroll
    for (int ch = 0; ch < 4; ch++) {
        float4 bb = *(const float4*)&b2[bn0 + cb + ch * 4];
        float kv[4] = { v[ch].x + bb.x, v[ch].y + bb.y, v[ch].z + bb.z, v[ch].w + bb.w };
        size_t idx = base + ch * 4;
        float4 zv = *(const float4*)&z[idx];
        float zn[4];
        if (mode == 0) {
            *(float4*)&kacc[idx] = make_float4(kv[0], kv[1], kv[2], kv[3]);
            zn[0] = zv.x + ah * kv[0]; zn[1] = zv.y + ah * kv[1];
            zn[2] = zv.z + ah * kv[2]; zn[3] = zv.w + ah * kv[3];
        } else if (mode == 1) {
            float4 ka = *(const float4*)&kacc[idx];
            *(float4*)&kacc[idx] = make_float4(ka.x + wk * kv[0], ka.y + wk * kv[1],
                                               ka.z + wk * kv[2], ka.w + wk * kv[3]);
            zn[0] = zv.x + ah * kv[0]; zn[1] = zv.y + ah * kv[1];
            zn[2] = zv.z + ah * kv[2]; zn[3] = zv.w + ah * kv[3];
        } else {
            float4 ka = *(const float4*)&kacc[idx];
            zn[0] = zv.x + h6 * (ka.x + kv[0]); zn[1] = zv.y + h6 * (ka.y + kv[1]);
            zn[2] = zv.z + h6 * (ka.z + kv[2]); zn[3] = zv.w + h6 * (ka.w + kv[3]);
            *(float4*)&z[idx] = make_float4(zn[0], zn[1], zn[2], zn[3]);
        }
        short4v o;
        o[0] = f2bf(zn[0]); o[1] = f2bf(zn[1]); o[2] = f2bf(zn[2]); o[3] = f2bf(zn[3]);
        *(short4v*)&abuf[idx] = o;
    }
}

extern "C" void kernel_launch(void* const* d_in, const int* in_sizes, int n_in,
                              void* d_out, int out_size, void* d_ws, size_t ws_size,
                              hipStream_t stream) {
    const float* z0  = (const float*)d_in[0];
    const float* W1  = (const float*)d_in[1];
    const float* b1  = (const float*)d_in[2];
    const float* W2  = (const float*)d_in[3];
    const float* b2  = (const float*)d_in[4];
    const float* t0p = (const float*)d_in[5];
    const float* t1p = (const float*)d_in[6];
    float* z = (float*)d_out;

    char* ws = (char*)d_ws;
    short* W1t    = (short*)(ws);                              // 2 MB
    short* W2t    = (short*)(ws + (2u << 20));                 // 2 MB
    float* w1last = (float*)(ws + (4u << 20));                 // 8 KB (pad 64 KB)
    short* abuf   = (short*)(ws + (4u << 20) + (1u << 16));    // 4 MB
    short* hidden = (short*)(ws + (8u << 20) + (1u << 16));    // 16 MB
    float* kacc   = (float*)(ws + (24u << 20) + (1u << 16));   // 8 MB

    hipMemcpyAsync(z, z0, (size_t)BATCH * DIM * sizeof(float),
                   hipMemcpyDeviceToDevice, stream);
    transpose_cvt<<<dim3(DIM / 32, HID / 32), dim3(32, 8), 0, stream>>>(W1, W1t, DIM, HID);
    transpose_cvt<<<dim3(HID / 32, DIM / 32), dim3(32, 8), 0, stream>>>(W2, W2t, HID, DIM);
    extract_row<<<HID / 256, 256, 0, stream>>>(W1, w1last);
    init_abuf<<<BATCH * DIM / 4 / 256, 256, 0, stream>>>(z0, abuf);

    const dim3 g1(BATCH / 128, HID / 64), g2(BATCH / 64, DIM / 64), b(256);
    for (int i = 0; i < NSTEPS; i++) {
        float fi = (float)i;
        // k1 -> abuf for k2
        gemm1_tanh<<<g1, b, 0, stream>>>(abuf, W1t, b1, w1last, t0p, t1p, 0.0f, fi, hidden);
        gemm2_fused<<<g2, b, 0, stream>>>(hidden, W2t, b2, z, kacc, abuf, t0p, t1p, 0, 1.0f, 0.5f);
        // k2 -> abuf for k3
        gemm1_tanh<<<g1, b, 0, stream>>>(abuf, W1t, b1, w1last, t0p, t1p, 0.5f, fi, hidden);
        gemm2_fused<<<g2, b, 0, stream>>>(hidden, W2t, b2, z, kacc, abuf, t0p, t1p, 1, 2.0f, 0.5f);
        // k3 -> abuf for k4
        gemm1_tanh<<<g1, b, 0, stream>>>(abuf, W1t, b1, w1last, t0p, t1p, 0.5f, fi, hidden);
        gemm2_fused<<<g2, b, 0, stream>>>(hidden, W2t, b2, z, kacc, abuf, t0p, t1p, 1, 2.0f, 1.0f);
        // k4: z += (h/6)*(kacc + k4) ; abuf = bf16(z_new)
        gemm1_tanh<<<g1, b, 0, stream>>>(abuf, W1t, b1, w1last, t0p, t1p, 1.0f, fi, hidden);
        gemm2_fused<<<g2, b, 0, stream>>>(hidden, W2t, b2, z, kacc, abuf, t0p, t1p, 2, 1.0f, 0.0f);
    }
}

// Round 8
// 3020.507 us; speedup vs baseline: 1.1936x; 1.0411x over previous
//
#include <hip/hip_runtime.h>
#include <hip/hip_bf16.h>

#define BATCH 4096
#define DIM   512
#define HID   2048
#define NSTEPS 20

typedef __attribute__((ext_vector_type(8))) short short8;
typedef __attribute__((ext_vector_type(4))) short short4v;
typedef __attribute__((ext_vector_type(4))) float floatx4;

#define GLL(dst, src) __builtin_amdgcn_global_load_lds( \
    (const __attribute__((address_space(1))) void*)(src), \
    (__attribute__((address_space(3))) void*)(dst), 16, 0, 0)

__device__ __forceinline__ short f2bf(float x) {
    union { float f; unsigned u; } v; v.f = x;
    unsigned r = v.u + 0x7fffu + ((v.u >> 16) & 1u);
    return (short)(r >> 16);
}

// tanh(x) = 1 - 2*rcp(1 + exp2(2*log2e*x)); saturates correctly at +-inf
__device__ __forceinline__ float fast_tanh(float x) {
    float e = __builtin_amdgcn_exp2f(x * 2.8853900817779268f);
    float r = __builtin_amdgcn_rcpf(1.0f + e);
    return 1.0f - 2.0f * r;
}

// dst[n][k] = bf16(src[k][n]); src is K x N row-major fp32
__global__ void transpose_cvt(const float* __restrict__ src, short* __restrict__ dst,
                              int K, int N) {
    __shared__ float tile[32][33];
    int k0 = blockIdx.x * 32, n0 = blockIdx.y * 32;
    int tx = threadIdx.x, ty = threadIdx.y;
    #pragma unroll
    for (int r = ty; r < 32; r += 8)
        tile[r][tx] = src[(size_t)(k0 + r) * N + n0 + tx];
    __syncthreads();
    #pragma unroll
    for (int r = ty; r < 32; r += 8)
        dst[(size_t)(n0 + r) * K + k0 + tx] = f2bf(tile[tx][r]);
}

__global__ void extract_row(const float* __restrict__ W1, float* __restrict__ w1last) {
    int i = blockIdx.x * 256 + threadIdx.x;
    w1last[i] = W1[(size_t)DIM * HID + i];
}

__global__ void init_abuf(const float* __restrict__ z0, short* __restrict__ abuf) {
    size_t i = (size_t)(blockIdx.x * 256 + threadIdx.x) * 4;
    float4 zv = *(const float4*)(z0 + i);
    short4v o;
    o[0] = f2bf(zv.x); o[1] = f2bf(zv.y); o[2] = f2bf(zv.z); o[3] = f2bf(zv.w);
    *(short4v*)(abuf + i) = o;
}

// hidden = tanh( A @ W1t^T + b1 + t*w1last ), bf16 out.
// 128x128 tile, BK=128 (single K-split? no: K=512 -> 4 iters, halving barrier
// drains vs BK=64), XOR-swizzled LDS, wave-tile 64x64, 2 blocks/CU (grid-
// limited anyway, so 64 KB LDS is free). Operand-swapped MFMA epilogue.
__global__ __launch_bounds__(256, 2)
void gemm1_tanh(const short* __restrict__ A, const short* __restrict__ Bt,
                const float* __restrict__ b1, const float* __restrict__ w1last,
                const float* __restrict__ t0p, const float* __restrict__ t1p,
                float c_t, float step_i,
                short* __restrict__ hidden) {
    __shared__ short Alds[128 * 128];   // 32 KB
    __shared__ short Blds[128 * 128];   // 32 KB
    const int tid = threadIdx.x;
    const int lane = tid & 63;
    const int wave = tid >> 6;
    const int wm = wave >> 1, wn = wave & 1;
    const int bm0 = blockIdx.x * 128;   // 32 blocks over M
    const int bn0 = blockIdx.y * 128;   // 16 blocks over N

    const float t0 = t0p[0], t1 = t1p[0];
    const float h = (t1 - t0) / (float)NSTEPS;
    const float teval = t0 + (step_i + c_t) * h;

    floatx4 acc[4][4];
    #pragma unroll
    for (int i = 0; i < 4; i++)
        #pragma unroll
        for (int j = 0; j < 4; j++) acc[i][j] = (floatx4)0.f;

    const int fr = lane & 15;
    const int fkc = lane >> 4;     // 0..3
    const int rx = fr & 7;

    for (int kk = 0; kk < DIM; kk += 128) {
        // stage A,B tiles 128x128: 2048 chunks of 16B each, 8/thread
        #pragma unroll
        for (int p = 0; p < 8; p++) {
            int c = tid + p * 256;
            int row = c >> 4;
            int ci = c & 15;
            int g = ((ci & 7) ^ (row & 7)) | (ci & 8);   // swizzle low 3 bits
            GLL(&Alds[c * 8], A  + (size_t)(bm0 + row) * DIM + kk + g * 8);
            GLL(&Blds[c * 8], Bt + (size_t)(bn0 + row) * DIM + kk + g * 8);
        }
        __syncthreads();               // forced vmcnt(0): staging landed
        #pragma unroll
        for (int s = 0; s < 4; s++) {
            const int lc = s * 4 + fkc;                       // logical chunk 0..15
            const int slot = ((((lc & 7) ^ rx) | (lc & 8))) * 8;
            short8 af[4], bfr[4];
            #pragma unroll
            for (int mt = 0; mt < 4; mt++)
                af[mt] = *(const short8*)&Alds[(wm * 64 + mt * 16 + fr) * 128 + slot];
            #pragma unroll
            for (int nt = 0; nt < 4; nt++)
                bfr[nt] = *(const short8*)&Blds[(wn * 64 + nt * 16 + fr) * 128 + slot];
            #pragma unroll
            for (int mt = 0; mt < 4; mt++)
                #pragma unroll
                for (int nt = 0; nt < 4; nt++)   // swapped: lane holds 4 consecutive cols
                    acc[mt][nt] = __builtin_amdgcn_mfma_f32_16x16x32_bf16(bfr[nt], af[mt], acc[mt][nt], 0, 0, 0);
        }
        __syncthreads();
    }
    // epilogue: lane = row m (fr); regs = 4 consecutive cols -> packed 8B stores
    #pragma unroll
    for (int mt = 0; mt < 4; mt++) {
        int m = bm0 + wm * 64 + mt * 16 + fr;
        short* hrow = hidden + (size_t)m * HID;
        #pragma unroll
        for (int nt = 0; nt < 4; nt++) {
            int n0 = bn0 + wn * 64 + nt * 16 + fkc * 4;
            float4 bb = *(const float4*)&b1[n0];
            float4 wl = *(const float4*)&w1last[n0];
            short4v o;
            o[0] = f2bf(fast_tanh(acc[mt][nt][0] + bb.x + teval * wl.x));
            o[1] = f2bf(fast_tanh(acc[mt][nt][1] + bb.y + teval * wl.y));
            o[2] = f2bf(fast_tanh(acc[mt][nt][2] + bb.z + teval * wl.z));
            o[3] = f2bf(fast_tanh(acc[mt][nt][3] + bb.w + teval * wl.w));
            *(short4v*)&hrow[n0] = o;
        }
    }
}

// k = hidden @ W2t^T + b2.  64x64 tile, 512 threads = 8-way K-split across
// waves (wave K=256, 4 iters of BK=64 -> half the vmcnt(0) drains of R4),
// per-wave private 16 KB LDS slab (128 KB total), NO barriers in K-loop.
// mode 0 (k1): kacc = k;            abuf = bf16(z + alpha*h*k)
// mode 1 (k2/k3): kacc += wk*k;     abuf = bf16(z + alpha*h*k)
// mode 2 (k4): z += (h/6)*(kacc+k); abuf = bf16(z_new)
__global__ __launch_bounds__(512, 2)
void gemm2_fused(const short* __restrict__ hidden,  // [BATCH][HID] bf16
                 const short* __restrict__ Bt,      // W2t [DIM][HID] bf16
                 const float* __restrict__ b2,
                 float* __restrict__ z,
                 float* __restrict__ kacc, short* __restrict__ abuf,
                 const float* __restrict__ t0p, const float* __restrict__ t1p,
                 int mode, float wk, float alpha_c) {
    __shared__ short lds[8 * 8192];    // 8 slabs x 16 KB (A[64][64] + B[64][64])
    const int tid = threadIdx.x;
    const int lane = tid & 63;
    const int wave = tid >> 6;          // K-split index 0..7
    const int bm0 = blockIdx.x * 64;    // 64 blocks over M
    const int bn0 = blockIdx.y * 64;    // 8 blocks over N
    const int kbase = wave * 256;

    short* slabA = &lds[wave * 8192];
    short* slabB = slabA + 4096;

    const int fr = lane & 15;
    const int fkc = lane >> 4;     // 0..3
    const int rx = fr & 7;
    const int l3 = lane >> 3;      // 0..7
    const int gch = (lane & 7) ^ l3;   // swizzled global k-chunk for staging

    floatx4 acc[4][4];
    #pragma unroll
    for (int i = 0; i < 4; i++)
        #pragma unroll
        for (int j = 0; j < 4; j++) acc[i][j] = (floatx4)0.f;

    #pragma unroll
    for (int it = 0; it < 4; ++it) {
        const int k0 = kbase + it * 64;
        // drain own ds_reads before overwriting slab (lgkmcnt(0), vmcnt don't-care)
        __builtin_amdgcn_s_waitcnt(0xC07F);
        #pragma unroll
        for (int j = 0; j < 8; j++) {
            int row = j * 8 + l3;
            GLL(&slabA[j * 512 + lane * 8], hidden + (size_t)(bm0 + row) * HID + k0 + gch * 8);
            GLL(&slabB[j * 512 + lane * 8], Bt     + (size_t)(bn0 + row) * HID + k0 + gch * 8);
        }
        __builtin_amdgcn_sched_barrier(0);
        __builtin_amdgcn_s_waitcnt(0x0F70);   // vmcnt(0) only, per-wave
        __builtin_amdgcn_sched_barrier(0);
        #pragma unroll
        for (int s = 0; s < 2; s++) {
            const int slot = ((s * 4 + fkc) ^ rx) * 8;
            short8 af[4], bfr[4];
            #pragma unroll
            for (int mt = 0; mt < 4; mt++)
                af[mt] = *(const short8*)&slabA[(mt * 16 + fr) * 64 + slot];
            #pragma unroll
            for (int nt = 0; nt < 4; nt++)
                bfr[nt] = *(const short8*)&slabB[(nt * 16 + fr) * 64 + slot];
            #pragma unroll
            for (int mt = 0; mt < 4; mt++)
                #pragma unroll
                for (int nt = 0; nt < 4; nt++)
                    acc[mt][nt] = __builtin_amdgcn_mfma_f32_16x16x32_bf16(af[mt], bfr[nt], acc[mt][nt], 0, 0, 0);
        }
        __builtin_amdgcn_sched_barrier(0);
    }

    // write partial acc (fp32 [64][64]) into own slab, then reduce across 8 waves
    float* fslab = (float*)slabA;
    #pragma unroll
    for (int mt = 0; mt < 4; mt++)
        #pragma unroll
        for (int nt = 0; nt < 4; nt++)
            #pragma unroll
            for (int r = 0; r < 4; r++) {
                int row = mt * 16 + fkc * 4 + r;
                int col = nt * 16 + fr;
                fslab[row * 64 + col] = acc[mt][nt][r];
            }
    __syncthreads();

    // 512 threads: each handles 1 row x 8 cols
    const int rrow = tid >> 3;          // 0..63
    const int c8 = (tid & 7) * 8;       // col chunk of 8
    float4 v0 = make_float4(0.f, 0.f, 0.f, 0.f);
    float4 v1 = make_float4(0.f, 0.f, 0.f, 0.f);
    #pragma unroll
    for (int w = 0; w < 8; w++) {
        const float* fs = (const float*)&lds[w * 8192];
        float4 p0 = *(const float4*)&fs[rrow * 64 + c8];
        float4 p1 = *(const float4*)&fs[rrow * 64 + c8 + 4];
        v0.x += p0.x; v0.y += p0.y; v0.z += p0.z; v0.w += p0.w;
        v1.x += p1.x; v1.y += p1.y; v1.z += p1.z; v1.w += p1.w;
    }

    const float h = (t1p[0] - t0p[0]) / (float)NSTEPS;
    const float ah = alpha_c * h;
    const float h6 = h / 6.0f;
    const size_t base = (size_t)(bm0 + rrow) * DIM + bn0 + c8;
    float4 bb0 = *(const float4*)&b2[bn0 + c8];
    float4 bb1 = *(const float4*)&b2[bn0 + c8 + 4];
    float kv[8] = { v0.x + bb0.x, v0.y + bb0.y, v0.z + bb0.z, v0.w + bb0.w,
                    v1.x + bb1.x, v1.y + bb1.y, v1.z + bb1.z, v1.w + bb1.w };
    float4 zv0 = *(const float4*)&z[base];
    float4 zv1 = *(const float4*)&z[base + 4];
    float zl[8] = { zv0.x, zv0.y, zv0.z, zv0.w, zv1.x, zv1.y, zv1.z, zv1.w };
    float zn[8];
    if (mode == 0) {
        *(float4*)&kacc[base]     = make_float4(kv[0], kv[1], kv[2], kv[3]);
        *(float4*)&kacc[base + 4] = make_float4(kv[4], kv[5], kv[6], kv[7]);
        #pragma unroll
        for (int i = 0; i < 8; i++) zn[i] = zl[i] + ah * kv[i];
    } else if (mode == 1) {
        float4 ka0 = *(const float4*)&kacc[base];
        float4 ka1 = *(const float4*)&kacc[base + 4];
        *(float4*)&kacc[base]     = make_float4(ka0.x + wk * kv[0], ka0.y + wk * kv[1],
                                                ka0.z + wk * kv[2], ka0.w + wk * kv[3]);
        *(float4*)&kacc[base + 4] = make_float4(ka1.x + wk * kv[4], ka1.y + wk * kv[5],
                                                ka1.z + wk * kv[6], ka1.w + wk * kv[7]);
        #pragma unroll
        for (int i = 0; i < 8; i++) zn[i] = zl[i] + ah * kv[i];
    } else {
        float4 ka0 = *(const float4*)&kacc[base];
        float4 ka1 = *(const float4*)&kacc[base + 4];
        float kaf[8] = { ka0.x, ka0.y, ka0.z, ka0.w, ka1.x, ka1.y, ka1.z, ka1.w };
        #pragma unroll
        for (int i = 0; i < 8; i++) zn[i] = zl[i] + h6 * (kaf[i] + kv[i]);
        *(float4*)&z[base]     = make_float4(zn[0], zn[1], zn[2], zn[3]);
        *(float4*)&z[base + 4] = make_float4(zn[4], zn[5], zn[6], zn[7]);
    }
    short4v o0, o1;
    o0[0] = f2bf(zn[0]); o0[1] = f2bf(zn[1]); o0[2] = f2bf(zn[2]); o0[3] = f2bf(zn[3]);
    o1[0] = f2bf(zn[4]); o1[1] = f2bf(zn[5]); o1[2] = f2bf(zn[6]); o1[3] = f2bf(zn[7]);
    *(short4v*)&abuf[base]     = o0;
    *(short4v*)&abuf[base + 4] = o1;
}

extern "C" void kernel_launch(void* const* d_in, const int* in_sizes, int n_in,
                              void* d_out, int out_size, void* d_ws, size_t ws_size,
                              hipStream_t stream) {
    const float* z0  = (const float*)d_in[0];
    const float* W1  = (const float*)d_in[1];
    const float* b1  = (const float*)d_in[2];
    const float* W2  = (const float*)d_in[3];
    const float* b2  = (const float*)d_in[4];
    const float* t0p = (const float*)d_in[5];
    const float* t1p = (const float*)d_in[6];
    float* z = (float*)d_out;

    char* ws = (char*)d_ws;
    short* W1t    = (short*)(ws);                              // 2 MB
    short* W2t    = (short*)(ws + (2u << 20));                 // 2 MB
    float* w1last = (float*)(ws + (4u << 20));                 // 8 KB (pad 64 KB)
    short* abuf   = (short*)(ws + (4u << 20) + (1u << 16));    // 4 MB
    short* hidden = (short*)(ws + (8u << 20) + (1u << 16));    // 16 MB
    float* kacc   = (float*)(ws + (24u << 20) + (1u << 16));   // 8 MB

    hipMemcpyAsync(z, z0, (size_t)BATCH * DIM * sizeof(float),
                   hipMemcpyDeviceToDevice, stream);
    transpose_cvt<<<dim3(DIM / 32, HID / 32), dim3(32, 8), 0, stream>>>(W1, W1t, DIM, HID);
    transpose_cvt<<<dim3(HID / 32, DIM / 32), dim3(32, 8), 0, stream>>>(W2, W2t, HID, DIM);
    extract_row<<<HID / 256, 256, 0, stream>>>(W1, w1last);
    init_abuf<<<BATCH * DIM / 4 / 256, 256, 0, stream>>>(z0, abuf);

    const dim3 g1(BATCH / 128, HID / 128), g2(BATCH / 64, DIM / 64);
    const dim3 b1d(256), b2d(512);
    for (int i = 0; i < NSTEPS; i++) {
        float fi = (float)i;
        // k1 -> abuf for k2
        gemm1_tanh<<<g1, b1d, 0, stream>>>(abuf, W1t, b1, w1last, t0p, t1p, 0.0f, fi, hidden);
        gemm2_fused<<<g2, b2d, 0, stream>>>(hidden, W2t, b2, z, kacc, abuf, t0p, t1p, 0, 1.0f, 0.5f);
        // k2 -> abuf for k3
        gemm1_tanh<<<g1, b1d, 0, stream>>>(abuf, W1t, b1, w1last, t0p, t1p, 0.5f, fi, hidden);
        gemm2_fused<<<g2, b2d, 0, stream>>>(hidden, W2t, b2, z, kacc, abuf, t0p, t1p, 1, 2.0f, 0.5f);
        // k3 -> abuf for k4
        gemm1_tanh<<<g1, b1d, 0, stream>>>(abuf, W1t, b1, w1last, t0p, t1p, 0.5f, fi, hidden);
        gemm2_fused<<<g2, b2d, 0, stream>>>(hidden, W2t, b2, z, kacc, abuf, t0p, t1p, 1, 2.0f, 1.0f);
        // k4: z += (h/6)*(kacc + k4) ; abuf = bf16(z_new)
        gemm1_tanh<<<g1, b1d, 0, stream>>>(abuf, W1t, b1, w1last, t0p, t1p, 1.0f, fi, hidden);
        gemm2_fused<<<g2, b2d, 0, stream>>>(hidden, W2t, b2, z, kacc, abuf, t0p, t1p, 2, 1.0f, 0.0f);
    }
}